// Round 1
// baseline (1363.032 us; speedup 1.0000x reference)
//
#include <hip/hip_runtime.h>

// SpikingLinear: lin = input[:-1] @ W^T  (fp32 GEMM, M=32512, N=1024, K=1024)
// then per-(b,o) temporal scan:
//   reset = (mem > 1);  syn = a*syn + cur;  mem = (b*mem + syn)*(1-reset);  spk = (mem > 1)
// Outputs (flat concat): spk[128,256,1024], V[128,256,1024], I[128,256,1024]
//
// Trick: GEMM writes lin[t] directly into the I-output slot at step t+1;
// the scan reads it there and overwrites in place with syn. No workspace.

#define STEPS 128
#define BATCH 256
#define DIN   1024
#define DOUT  1024

#define ALPHA 0.7788007830714049f   // exp(-1/4)
#define BETA  0.9512294245007140f   // exp(-1/20)

constexpr int GM = (STEPS - 1) * BATCH;   // 32512 GEMM rows
constexpr int BM = 64, BN = 64, BK = 32;
constexpr int PAD = 4;                    // keeps LDS float4 reads 16B-aligned

__global__ __launch_bounds__(256)
void gemm_kernel(const float* __restrict__ A,   // [GM, DIN] = input rows 0..32511
                 const float* __restrict__ W,   // [DOUT, DIN]
                 float* __restrict__ C)         // lin target: out2 + BATCH*DOUT
{
    __shared__ float As[BK][BM + PAD];
    __shared__ float Ws[BK][BN + PAD];

    const int tid = threadIdx.x;
    const int m0  = blockIdx.y * BM;
    const int n0  = blockIdx.x * BN;
    const int tx  = tid & 15;   // n micro index (0..15)
    const int ty  = tid >> 4;   // m micro index (0..15)

    float acc[4][4] = {};

    for (int k0 = 0; k0 < DIN; k0 += BK) {
        // stage A-tile and W-tile (each 64 rows x 32 k), 2 float4 granules/thread
        #pragma unroll
        for (int g = 0; g < 2; ++g) {
            const int gid = tid + g * 256;      // 0..511
            const int row = gid >> 3;           // 0..63
            const int kq  = gid & 7;            // 0..7  (float4 granule along k)
            const float4 av = *reinterpret_cast<const float4*>(
                &A[(size_t)(m0 + row) * DIN + k0 + kq * 4]);
            As[kq * 4 + 0][row] = av.x;
            As[kq * 4 + 1][row] = av.y;
            As[kq * 4 + 2][row] = av.z;
            As[kq * 4 + 3][row] = av.w;
            const float4 wv = *reinterpret_cast<const float4*>(
                &W[(size_t)(n0 + row) * DIN + k0 + kq * 4]);
            Ws[kq * 4 + 0][row] = wv.x;
            Ws[kq * 4 + 1][row] = wv.y;
            Ws[kq * 4 + 2][row] = wv.z;
            Ws[kq * 4 + 3][row] = wv.w;
        }
        __syncthreads();

        #pragma unroll
        for (int k = 0; k < BK; ++k) {
            const float4 a = *reinterpret_cast<const float4*>(&As[k][ty * 4]);
            const float4 b = *reinterpret_cast<const float4*>(&Ws[k][tx * 4]);
            const float av4[4] = {a.x, a.y, a.z, a.w};
            const float bv4[4] = {b.x, b.y, b.z, b.w};
            #pragma unroll
            for (int i = 0; i < 4; ++i)
                #pragma unroll
                for (int j = 0; j < 4; ++j)
                    acc[i][j] = fmaf(av4[i], bv4[j], acc[i][j]);
        }
        __syncthreads();
    }

    #pragma unroll
    for (int i = 0; i < 4; ++i) {
        float4 v = make_float4(acc[i][0], acc[i][1], acc[i][2], acc[i][3]);
        *reinterpret_cast<float4*>(
            &C[(size_t)(m0 + ty * 4 + i) * DOUT + n0 + tx * 4]) = v;
    }
}

__global__ __launch_bounds__(256)
void scan_kernel(float* __restrict__ out)
{
    const int idx = blockIdx.x * 256 + threadIdx.x;   // (b,o) flat, o fastest
    const size_t plane = (size_t)BATCH * DOUT;        // elems per step
    float* out0 = out;                                 // spk
    float* out1 = out + (size_t)STEPS * plane;         // V
    float* out2 = out + 2 * (size_t)STEPS * plane;     // I (holds lin at steps>=1)

    // step 0 stays zero for all three outputs
    out0[idx] = 0.0f;
    out1[idx] = 0.0f;
    out2[idx] = 0.0f;

    float syn = 0.0f, mem = 0.0f;
    size_t off = idx;
    for (int i = 1; i < STEPS; ++i) {
        off += plane;
        const float cur   = out2[off];                 // lin[i-1]
        const float reset = (mem > 1.0f) ? 1.0f : 0.0f;
        syn = ALPHA * syn + cur;
        mem = (BETA * mem + syn) * (1.0f - reset);
        const float spk = (mem > 1.0f) ? 1.0f : 0.0f;
        out0[off] = spk;
        out1[off] = mem;
        out2[off] = syn;                                // overwrite lin with I
    }
}

extern "C" void kernel_launch(void* const* d_in, const int* in_sizes, int n_in,
                              void* d_out, int out_size, void* d_ws, size_t ws_size,
                              hipStream_t stream)
{
    const float* input  = (const float*)d_in[0];   // [128, 256, 1024]
    const float* weight = (const float*)d_in[1];   // [1024, 1024]
    float* out = (float*)d_out;

    const size_t plane = (size_t)BATCH * DOUT;
    // lin[m] (m = t*BATCH+b, t in [0,127)) lands at out2 step t+1
    float* lin = out + 2 * (size_t)STEPS * plane + plane;

    dim3 ggrid(DOUT / BN, GM / BM);   // (16, 508)
    gemm_kernel<<<ggrid, 256, 0, stream>>>(input, weight, lin);

    scan_kernel<<<(BATCH * DOUT) / 256, 256, 0, stream>>>(out);
}

// Round 2
// 719.991 us; speedup vs baseline: 1.8931x; 1.8931x over previous
//
#include <hip/hip_runtime.h>
#include <hip/hip_bf16.h>

// SpikingLinear on MI355X:
//   lin = input[:-1] @ W^T   (M=32512, N=1024, K=1024)  via split-bf16 MFMA:
//     A = A_hi + A_lo, W = W_hi + W_lo  (bf16 round-nearest splits)
//     lin ~= Ah*Wh + Ah*Wl + Al*Wh      (3x mfma_f32_16x16x32_bf16, fp32 acc)
//   then per-(b,o) temporal scan (syn/mem/spk), in-place in the output buffer.
//
// Buffer reuse (no d_ws): A_hi/A_lo stored in the spk-output plane (133.2MB
// of 134.2MB), W_hi/W_lo in the V-output plane (4MB). GEMM writes lin into
// the I-output plane at step t+1. Scan overwrites everything afterwards.
// All kernels serialized on `stream`.

#define STEPS 128
#define BATCH 256
#define DIN   1024
#define DOUT  1024

#define ALPHA 0.7788007830714049f   // exp(-1/4)
#define BETA  0.9512294245007140f   // exp(-1/20)

constexpr int    GM      = (STEPS - 1) * BATCH;        // 32512 GEMM rows
constexpr size_t PLANE   = (size_t)BATCH * DOUT;       // 262144 elems / step
constexpr size_t A_ELEMS = (size_t)GM * DIN;           // 33,292,288
constexpr size_t W_ELEMS = (size_t)DOUT * DIN;         // 1,048,576

typedef __attribute__((ext_vector_type(8))) short short8;   // 8 bf16 = 4 VGPR
typedef __attribute__((ext_vector_type(4))) float float4v;  // MFMA C/D

// ---------------------------------------------------------------- split ----
__global__ __launch_bounds__(256)
void split_kernel(const float* __restrict__ x,
                  __hip_bfloat16* __restrict__ hi,
                  __hip_bfloat16* __restrict__ lo)
{
    const size_t i = (size_t)blockIdx.x * 256 + threadIdx.x;   // float4 index
    const float4 v = reinterpret_cast<const float4*>(x)[i];
    float f[4] = {v.x, v.y, v.z, v.w};
    unsigned short hb[4], lb[4];
#pragma unroll
    for (int j = 0; j < 4; ++j) {
        __hip_bfloat16 h = __float2bfloat16(f[j]);
        __hip_bfloat16 l = __float2bfloat16(f[j] - __bfloat162float(h));
        hb[j] = *reinterpret_cast<unsigned short*>(&h);
        lb[j] = *reinterpret_cast<unsigned short*>(&l);
    }
    ushort4 hv = {hb[0], hb[1], hb[2], hb[3]};
    ushort4 lv = {lb[0], lb[1], lb[2], lb[3]};
    *reinterpret_cast<ushort4*>(hi + i * 4) = hv;
    *reinterpret_cast<ushort4*>(lo + i * 4) = lv;
}

// ----------------------------------------------------------------- gemm ----
__device__ __forceinline__ void load16(const unsigned short* g, unsigned short* l)
{
    __builtin_amdgcn_global_load_lds(
        (const __attribute__((address_space(1))) void*)g,
        (__attribute__((address_space(3))) void*)l, 16, 0, 0);
}

__global__ __launch_bounds__(256)
void gemm_kernel(const unsigned short* __restrict__ Ah,
                 const unsigned short* __restrict__ Al,
                 const unsigned short* __restrict__ Wh,
                 const unsigned short* __restrict__ Wl,
                 float* __restrict__ C)
{
    // 4 arrays x 128 rows x 32 k bf16 = 4 x 8KB = 32 KB
    __shared__ __align__(16) unsigned short smem[4 * 4096];

    const int t    = threadIdx.x;
    const int wave = t >> 6, lane = t & 63;
    const int m0   = blockIdx.y * 128;
    const int n0   = blockIdx.x * 128;

    // staging: slot = row*4 + kg (16B granules); pass p covers rows p*64..p*64+63
    const int srow = t >> 2, skg = t & 3;
    const size_t offA = (size_t)(m0 + srow) * DIN + skg * 8;
    const size_t offB = (size_t)(n0 + srow) * DIN + skg * 8;
    unsigned short* lds0 = smem + (size_t)(wave * 64) * 8;         // pass 0 dest
    unsigned short* lds1 = smem + (size_t)(256 + wave * 64) * 8;   // pass 1 dest

    const int wr = wave >> 1, wc = wave & 1;   // wave -> 64x64 quadrant
    const int lr = lane & 15, q = lane >> 4;

    float4v acc[4][4];
#pragma unroll
    for (int i = 0; i < 4; ++i)
#pragma unroll
        for (int j = 0; j < 4; ++j)
            acc[i][j] = (float4v){0.f, 0.f, 0.f, 0.f};

    for (int k0 = 0; k0 < DIN; k0 += 32) {
        const unsigned short* pAh = Ah + offA + k0;
        const unsigned short* pAl = Al + offA + k0;
        const unsigned short* pBh = Wh + offB + k0;
        const unsigned short* pBl = Wl + offB + k0;
        load16(pAh,            lds0);
        load16(pAh + 64 * DIN, lds1);
        load16(pAl,            lds0 + 4096);
        load16(pAl + 64 * DIN, lds1 + 4096);
        load16(pBh,            lds0 + 8192);
        load16(pBh + 64 * DIN, lds1 + 8192);
        load16(pBl,            lds0 + 12288);
        load16(pBl + 64 * DIN, lds1 + 12288);
        __syncthreads();   // compiler drains vmcnt before s_barrier

        short8 ah[4], al[4], bh[4], bl[4];
#pragma unroll
        for (int i = 0; i < 4; ++i) {
            const int r = wr * 64 + i * 16 + lr;
            ah[i] = *reinterpret_cast<const short8*>(smem +        r * 32 + q * 8);
            al[i] = *reinterpret_cast<const short8*>(smem + 4096 + r * 32 + q * 8);
        }
#pragma unroll
        for (int j = 0; j < 4; ++j) {
            const int r = wc * 64 + j * 16 + lr;
            bh[j] = *reinterpret_cast<const short8*>(smem + 8192  + r * 32 + q * 8);
            bl[j] = *reinterpret_cast<const short8*>(smem + 12288 + r * 32 + q * 8);
        }
#pragma unroll
        for (int i = 0; i < 4; ++i)
#pragma unroll
            for (int j = 0; j < 4; ++j) {
                acc[i][j] = __builtin_amdgcn_mfma_f32_16x16x32_bf16(ah[i], bh[j], acc[i][j], 0, 0, 0);
                acc[i][j] = __builtin_amdgcn_mfma_f32_16x16x32_bf16(ah[i], bl[j], acc[i][j], 0, 0, 0);
                acc[i][j] = __builtin_amdgcn_mfma_f32_16x16x32_bf16(al[i], bh[j], acc[i][j], 0, 0, 0);
            }
        __syncthreads();
    }

    // C/D layout: col = lane&15, row = (lane>>4)*4 + reg   [m89/m91 verified]
#pragma unroll
    for (int i = 0; i < 4; ++i) {
        const int mrow = m0 + wr * 64 + i * 16 + q * 4;
#pragma unroll
        for (int j = 0; j < 4; ++j) {
            const int ncol = n0 + wc * 64 + j * 16 + lr;
#pragma unroll
            for (int rg = 0; rg < 4; ++rg)
                C[(size_t)(mrow + rg) * DOUT + ncol] = acc[i][j][rg];
        }
    }
}

// ----------------------------------------------------------------- scan ----
__global__ __launch_bounds__(256)
void scan_kernel(float* __restrict__ out)
{
    const int idx = blockIdx.x * 256 + threadIdx.x;   // (b,o) flat
    float* o0 = out;                                   // spk
    float* o1 = out + STEPS * PLANE;                   // V
    float* o2 = out + 2 * STEPS * PLANE;               // I (holds lin at t>=1)

    __builtin_nontemporal_store(0.0f, &o0[idx]);
    __builtin_nontemporal_store(0.0f, &o1[idx]);
    __builtin_nontemporal_store(0.0f, &o2[idx]);

    // depth-3 prefetch of lin reads
    float n1 = o2[idx + PLANE];
    float n2 = o2[idx + 2 * PLANE];
    float n3 = o2[idx + 3 * PLANE];

    float syn = 0.0f, mem = 0.0f;
    size_t off = idx;
    for (int i = 1; i < STEPS; ++i) {
        off += PLANE;
        const float cur = n1; n1 = n2; n2 = n3;
        if (i + 3 < STEPS) n3 = o2[off + 3 * PLANE];
        const float reset = (mem > 1.0f) ? 1.0f : 0.0f;
        syn = ALPHA * syn + cur;
        mem = (BETA * mem + syn) * (1.0f - reset);
        const float spk = (mem > 1.0f) ? 1.0f : 0.0f;
        __builtin_nontemporal_store(spk, &o0[off]);
        __builtin_nontemporal_store(mem, &o1[off]);
        __builtin_nontemporal_store(syn, &o2[off]);
    }
}

// --------------------------------------------------------------- launch ----
extern "C" void kernel_launch(void* const* d_in, const int* in_sizes, int n_in,
                              void* d_out, int out_size, void* d_ws, size_t ws_size,
                              hipStream_t stream)
{
    const float* input  = (const float*)d_in[0];   // [128, 256, 1024]
    const float* weight = (const float*)d_in[1];   // [1024, 1024]
    float* out = (float*)d_out;

    __hip_bfloat16* Ah = (__hip_bfloat16*)out;                     // spk plane
    __hip_bfloat16* Al = Ah + A_ELEMS;                             // 133.2MB < 134.2MB
    __hip_bfloat16* Wh = (__hip_bfloat16*)(out + STEPS * PLANE);   // V plane
    __hip_bfloat16* Wl = Wh + W_ELEMS;
    float* lin = out + 2 * STEPS * PLANE + PLANE;                  // I plane, t>=1

    split_kernel<<<(int)(A_ELEMS / 1024), 256, 0, stream>>>(input, Ah, Al);
    split_kernel<<<(int)(W_ELEMS / 1024), 256, 0, stream>>>(weight, Wh, Wl);

    gemm_kernel<<<dim3(DOUT / 128, GM / 128), 256, 0, stream>>>(
        (const unsigned short*)Ah, (const unsigned short*)Al,
        (const unsigned short*)Wh, (const unsigned short*)Wl, lin);

    scan_kernel<<<(int)(PLANE / 256), 256, 0, stream>>>(out);
}